// Round 1
// baseline (940.400 us; speedup 1.0000x reference)
//
#include <hip/hip_runtime.h>
#include <math.h>

typedef float vf4 __attribute__((ext_vector_type(4)));

#define CODE_SIZE 1024
#define CODE_DIM  256
#define BB        64
#define HWSZ      1024                       // H*W = 32*32
#define NROWS     (BB * HWSZ)                // 65536
#define QELEMS    (BB * CODE_DIM * HWSZ)     // 16777216

// ---------------------------------------------------------------------------
// sw[code] = numpy-pairwise sum of fl(w*w) over 256 contiguous elements.
// numpy pairwise for n=256: two halves of 128; each half = 8 accumulators
// (r[j]=a[j]; for i=8..120 step 8: r[j]+=a[i+j]) combined as
// ((r0+r1)+(r2+r3))+((r4+r5)+(r6+r7)); total = half0 + half1.
// ---------------------------------------------------------------------------
__global__ void k_sumsq_w(const float* __restrict__ w, float* __restrict__ sw) {
#pragma clang fp contract(off)
  const int code = blockIdx.x * blockDim.x + threadIdx.x;
  if (code >= CODE_SIZE) return;
  const float* row = w + (size_t)code * CODE_DIM;
  float halves[2];
  for (int h = 0; h < 2; ++h) {
    const float* p = row + h * 128;
    float r[8];
#pragma unroll
    for (int j = 0; j < 8; ++j) { float v = p[j]; r[j] = v * v; }
    for (int i = 8; i < 128; i += 8) {
#pragma unroll
      for (int j = 0; j < 8; ++j) { float v = p[i + j]; r[j] += v * v; }
    }
    halves[h] = ((r[0] + r[1]) + (r[2] + r[3])) + ((r[4] + r[5]) + (r[6] + r[7]));
  }
  sw[code] = halves[0] + halves[1];
}

// sx[n] = same pairwise over fl(x*x), x strided by HWSZ along channel dim.
__global__ void k_sumsq_x(const float* __restrict__ x, float* __restrict__ sx) {
#pragma clang fp contract(off)
  const int n = blockIdx.x * blockDim.x + threadIdx.x;   // 0..65535
  const int b = n >> 10, hw = n & 1023;
  const float* p = x + (size_t)b * CODE_DIM * HWSZ + hw;
  float halves[2];
  for (int h = 0; h < 2; ++h) {
    const float* q = p + (size_t)(h * 128) * HWSZ;
    float r[8];
#pragma unroll
    for (int j = 0; j < 8; ++j) { float v = q[(size_t)j * HWSZ]; r[j] = v * v; }
    for (int i = 8; i < 128; i += 8) {
#pragma unroll
      for (int j = 0; j < 8; ++j) { float v = q[(size_t)(i + j) * HWSZ]; r[j] += v * v; }
    }
    halves[h] = ((r[0] + r[1]) + (r[2] + r[3])) + ((r[4] + r[5]) + (r[6] + r[7]));
  }
  sx[n] = halves[0] + halves[1];
}

// ---------------------------------------------------------------------------
// Main GEMM-argmin. One workgroup = 64 rows x all 1024 codes (16 chunks of 64).
// Per-(row,code) accumulator is a single sequential fmaf chain over k=0..255 —
// bitwise-matching the BLAS sgemm micro-kernel accumulation the np ref uses.
// Key = fl(fl(sx - 2*G) + sw) with contract OFF (replicates np's d2 rounding).
// Tie-break: lowest code index everywhere.
// ---------------------------------------------------------------------------
#define MT 64
#define NT 64
#define NCHUNKS (CODE_SIZE / NT)

__launch_bounds__(256, 1)
__global__ void k_argmin(const float* __restrict__ x, const float* __restrict__ w,
                         const float* __restrict__ sx, const float* __restrict__ sw,
                         float* __restrict__ oidx) {
  __shared__ float xs[CODE_DIM * MT];   // xs[k][r], 64 KB
  __shared__ float ws[CODE_DIM * NT];   // ws[k][j], 64 KB
  __shared__ float redk[16 * MT];
  __shared__ int   redi[16 * MT];

  const int t   = threadIdx.x;
  const int n0  = blockIdx.x * MT;
  const int b   = n0 >> 10;
  const int hw0 = n0 & 1023;
  const int rt  = t & 15;    // row-group 0..15  (rows 4*rt..4*rt+3)
  const int ct  = t >> 4;    // code-group 0..15 (codes 4*ct..4*ct+3 per chunk)

  // stage xs[k][r] = x[b, k, hw0+r]  (coalesced float4 along rows)
  {
    const int r4 = rt * 4;
#pragma unroll
    for (int i = 0; i < 16; ++i) {
      const int c = ct + 16 * i;
      vf4 v = *(const vf4*)(x + ((size_t)(b * CODE_DIM + c) * HWSZ + hw0 + r4));
      *(vf4*)(xs + c * MT + r4) = v;
    }
  }

  float sxr[4];
#pragma unroll
  for (int ri = 0; ri < 4; ++ri) sxr[ri] = sx[n0 + rt * 4 + ri];

  float bk[4]; int bi[4];
#pragma unroll
  for (int ri = 0; ri < 4; ++ri) { bk[ri] = INFINITY; bi[ri] = CODE_SIZE; }

  for (int chunk = 0; chunk < NCHUNKS; ++chunk) {
    const int code0 = chunk * NT;
    __syncthreads();   // protect ws from previous chunk's readers
    // stage ws[k][j] = w[code0+j, k]  (conflict-free LDS writes, lanes span j)
    {
      const int j  = t & 63;
      const int cq = t >> 6;   // 0..3
#pragma unroll
      for (int i = 0; i < 16; ++i) {
        const int c4 = cq * 16 + i;
        vf4 v = *(const vf4*)(w + ((size_t)(code0 + j) * CODE_DIM + 4 * c4));
        ws[(4 * c4 + 0) * NT + j] = v.x;
        ws[(4 * c4 + 1) * NT + j] = v.y;
        ws[(4 * c4 + 2) * NT + j] = v.z;
        ws[(4 * c4 + 3) * NT + j] = v.w;
      }
    }
    __syncthreads();

    float acc[4][4];
#pragma unroll
    for (int ri = 0; ri < 4; ++ri)
#pragma unroll
      for (int cj = 0; cj < 4; ++cj) acc[ri][cj] = 0.0f;

    const float* xp = xs + rt * 4;
    const float* wp = ws + ct * 4;
#pragma unroll 4
    for (int k = 0; k < CODE_DIM; ++k) {
      vf4 xv = *(const vf4*)(xp + k * MT);
      vf4 wv = *(const vf4*)(wp + k * NT);
#pragma unroll
      for (int ri = 0; ri < 4; ++ri)
#pragma unroll
        for (int cj = 0; cj < 4; ++cj)
          acc[ri][cj] = fmaf(xv[ri], wv[cj], acc[ri][cj]);
    }

    {
#pragma clang fp contract(off)
#pragma unroll
      for (int cj = 0; cj < 4; ++cj) {
        const int code = code0 + ct * 4 + cj;
        const float swv = sw[code];
#pragma unroll
        for (int ri = 0; ri < 4; ++ri) {
          const float tmp = sxr[ri] - 2.0f * acc[ri][cj];  // fl(sx - 2G)
          const float key = tmp + swv;                     // fl(.. + sw)
          if (key < bk[ri] || (key == bk[ri] && code < bi[ri])) {
            bk[ri] = key; bi[ri] = code;
          }
        }
      }
    }
  }

#pragma unroll
  for (int ri = 0; ri < 4; ++ri) {
    redk[ct * MT + rt * 4 + ri] = bk[ri];
    redi[ct * MT + rt * 4 + ri] = bi[ri];
  }
  __syncthreads();
  if (t < MT) {
    float k0 = redk[t]; int i0 = redi[t];
#pragma unroll
    for (int q = 1; q < 16; ++q) {
      const float kq = redk[q * MT + t];
      const int   iq = redi[q * MT + t];
      if (kq < k0 || (kq == k0 && iq < i0)) { k0 = kq; i0 = iq; }
    }
    oidx[n0 + t] = (float)i0;   // idx output region read back as fp32
  }
}

// ---------------------------------------------------------------------------
// Epilogue: quantized gather + straight-through estimator.
// quantized[b,c,h,w] = w[idx[b,h,w]][c];  ste = fl(fl(q - x) + x).
// ---------------------------------------------------------------------------
__global__ void k_epilogue(const float* __restrict__ x, const float* __restrict__ w,
                           const float* __restrict__ oidx, float* __restrict__ out) {
#pragma clang fp contract(off)
  const int e  = blockIdx.x * blockDim.x + threadIdx.x;  // 0..4194303
  const int b  = e >> 16;
  const int c  = (e >> 8) & 255;
  const int hw = (e & 255) * 4;
  const size_t xoff = (size_t)(b * CODE_DIM + c) * HWSZ + hw;
  const int n = (b << 10) + hw;
  vf4 xv = *(const vf4*)(x + xoff);
  vf4 q, s;
#pragma unroll
  for (int u = 0; u < 4; ++u) {
    const int idx = (int)oidx[n + u];
    const float qv = w[(size_t)idx * CODE_DIM + c];
    q[u] = qv;
    const float d = qv - xv[u];
    s[u] = d + xv[u];
  }
  *(vf4*)(out + xoff) = q;
  *(vf4*)(out + (size_t)QELEMS + xoff) = s;
}

extern "C" void kernel_launch(void* const* d_in, const int* in_sizes, int n_in,
                              void* d_out, int out_size, void* d_ws, size_t ws_size,
                              hipStream_t stream) {
  const float* x = (const float*)d_in[0];   // (64,256,32,32) fp32
  const float* w = (const float*)d_in[1];   // (1024,256) fp32
  float* out  = (float*)d_out;
  float* oidx = out + 2 * (size_t)QELEMS;          // idx region (written as float)
  // scratch for sx/sw lives inside the ste region; epilogue overwrites it later
  float* sx = out + (size_t)QELEMS;                // 65536 floats
  float* sw = out + (size_t)QELEMS + NROWS;        // 1024 floats

  k_sumsq_w<<<CODE_SIZE / 256, 256, 0, stream>>>(w, sw);
  k_sumsq_x<<<NROWS / 256, 256, 0, stream>>>(x, sx);
  k_argmin<<<NROWS / MT, 256, 0, stream>>>(x, w, sx, sw, oidx);
  k_epilogue<<<QELEMS / 4 / 256, 256, 0, stream>>>(x, w, oidx, out);
}

// Round 2
// 706.036 us; speedup vs baseline: 1.3319x; 1.3319x over previous
//
#include <hip/hip_runtime.h>
#include <math.h>

typedef float vf4 __attribute__((ext_vector_type(4)));

#define CODE_SIZE 1024
#define CODE_DIM  256
#define BB        64
#define HWSZ      1024                       // H*W = 32*32
#define NROWS     (BB * HWSZ)                // 65536
#define QELEMS    (BB * CODE_DIM * HWSZ)     // 16777216

// ---------------------------------------------------------------------------
// sw[code] = numpy-pairwise sum of fl(w*w) over 256 contiguous elements.
// numpy pairwise for n=256: two halves of 128; each half = 8 accumulators
// combined as ((r0+r1)+(r2+r3))+((r4+r5)+(r6+r7)); total = half0 + half1.
// ---------------------------------------------------------------------------
__global__ void k_sumsq_w(const float* __restrict__ w, float* __restrict__ sw) {
#pragma clang fp contract(off)
  const int code = blockIdx.x * blockDim.x + threadIdx.x;
  if (code >= CODE_SIZE) return;
  const float* row = w + (size_t)code * CODE_DIM;
  float halves[2];
  for (int h = 0; h < 2; ++h) {
    const float* p = row + h * 128;
    float r[8];
#pragma unroll
    for (int j = 0; j < 8; ++j) { float v = p[j]; r[j] = v * v; }
    for (int i = 8; i < 128; i += 8) {
#pragma unroll
      for (int j = 0; j < 8; ++j) { float v = p[i + j]; r[j] += v * v; }
    }
    halves[h] = ((r[0] + r[1]) + (r[2] + r[3])) + ((r[4] + r[5]) + (r[6] + r[7]));
  }
  sw[code] = halves[0] + halves[1];
}

// sx[n] = same pairwise over fl(x*x), x strided by HWSZ along channel dim.
__global__ void k_sumsq_x(const float* __restrict__ x, float* __restrict__ sx) {
#pragma clang fp contract(off)
  const int n = blockIdx.x * blockDim.x + threadIdx.x;   // 0..65535
  const int b = n >> 10, hw = n & 1023;
  const float* p = x + (size_t)b * CODE_DIM * HWSZ + hw;
  float halves[2];
  for (int h = 0; h < 2; ++h) {
    const float* q = p + (size_t)(h * 128) * HWSZ;
    float r[8];
#pragma unroll
    for (int j = 0; j < 8; ++j) { float v = q[(size_t)j * HWSZ]; r[j] = v * v; }
    for (int i = 8; i < 128; i += 8) {
#pragma unroll
      for (int j = 0; j < 8; ++j) { float v = q[(size_t)(i + j) * HWSZ]; r[j] += v * v; }
    }
    halves[h] = ((r[0] + r[1]) + (r[2] + r[3])) + ((r[4] + r[5]) + (r[6] + r[7]));
  }
  sx[n] = halves[0] + halves[1];
}

// ---------------------------------------------------------------------------
// Main GEMM-argmin. One workgroup = 64 rows x all 1024 codes (16 chunks of 64).
// K is processed in 4 chunks of 64 so LDS = 16+16+8 = 40 KB -> 3-4 blocks/CU
// (round-1 was 136 KB -> 1 block/CU -> 1 wave/SIMD -> VALUBusy 42%).
// Per-(row,code) accumulator remains a single sequential fmaf chain over
// k=0..255 (kc-outer loop preserves order) — bitwise-matching np's sgemm.
// Key = fl(fl(sx - 2*G) + sw) with contract OFF. Tie-break: lowest index.
// ---------------------------------------------------------------------------
#define MT 64
#define NT 64
#define KC 64
#define NCHUNKS (CODE_SIZE / NT)

__launch_bounds__(256, 4)
__global__ void k_argmin(const float* __restrict__ x, const float* __restrict__ w,
                         const float* __restrict__ sx, const float* __restrict__ sw,
                         float* __restrict__ oidx) {
  __shared__ float xs[KC * MT];       // 16 KB: xs[k][r]
  __shared__ float ws[KC * NT];       // 16 KB: ws[k][j]
  __shared__ float redk[4 * MT];      // final cross-thread min-merge
  __shared__ int   redi[4 * MT];

  const int t   = threadIdx.x;
  const int n0  = blockIdx.x * MT;
  const int b   = n0 >> 10;
  const int hw0 = n0 & 1023;
  const int rt  = t & 15;    // row-group 0..15  (rows 4*rt..4*rt+3)
  const int ct  = t >> 4;    // code-group 0..15 (codes 4*ct..4*ct+3 per chunk)

  float sxr[4];
#pragma unroll
  for (int ri = 0; ri < 4; ++ri) sxr[ri] = sx[n0 + rt * 4 + ri];

  float bk[4]; int bi[4];
#pragma unroll
  for (int ri = 0; ri < 4; ++ri) { bk[ri] = INFINITY; bi[ri] = CODE_SIZE; }

  for (int chunk = 0; chunk < NCHUNKS; ++chunk) {
    const int code0 = chunk * NT;

    float acc[4][4];
#pragma unroll
    for (int ri = 0; ri < 4; ++ri)
#pragma unroll
      for (int cj = 0; cj < 4; ++cj) acc[ri][cj] = 0.0f;

    for (int kc = 0; kc < CODE_DIM / KC; ++kc) {
      const int kbase = kc * KC;
      __syncthreads();   // protect xs/ws from previous iteration's readers
      // stage xs[k][r] = x[b, kbase+k, hw0+r]  (coalesced float4 along rows)
      {
        const int r4 = rt * 4;
        const int kk = t >> 4;   // 0..15
#pragma unroll
        for (int i = 0; i < 4; ++i) {
          const int k = kk + 16 * i;
          vf4 v = *(const vf4*)(x + ((size_t)(b * CODE_DIM + kbase + k) * HWSZ + hw0 + r4));
          *(vf4*)(xs + k * MT + r4) = v;
        }
      }
      // stage ws[k][j] = w[code0+j, kbase+k]  (lanes span j -> conflict-free)
      {
        const int j  = t & 63;
        const int cq = t >> 6;   // 0..3
#pragma unroll
        for (int i = 0; i < 4; ++i) {
          const int c4 = cq * 4 + i;   // 0..15, covers k = 4*c4..4*c4+3
          vf4 v = *(const vf4*)(w + ((size_t)(code0 + j) * CODE_DIM + kbase + 4 * c4));
          ws[(4 * c4 + 0) * NT + j] = v.x;
          ws[(4 * c4 + 1) * NT + j] = v.y;
          ws[(4 * c4 + 2) * NT + j] = v.z;
          ws[(4 * c4 + 3) * NT + j] = v.w;
        }
      }
      __syncthreads();

      const float* xp = xs + rt * 4;
      const float* wp = ws + ct * 4;
#pragma unroll 4
      for (int k = 0; k < KC; ++k) {
        vf4 xv = *(const vf4*)(xp + k * MT);
        vf4 wv = *(const vf4*)(wp + k * NT);
#pragma unroll
        for (int ri = 0; ri < 4; ++ri)
#pragma unroll
          for (int cj = 0; cj < 4; ++cj)
            acc[ri][cj] = fmaf(xv[ri], wv[cj], acc[ri][cj]);
      }
    }

    {
#pragma clang fp contract(off)
#pragma unroll
      for (int cj = 0; cj < 4; ++cj) {
        const int code = code0 + ct * 4 + cj;
        const float swv = sw[code];
#pragma unroll
        for (int ri = 0; ri < 4; ++ri) {
          const float tmp = sxr[ri] - 2.0f * acc[ri][cj];  // fl(sx - 2G)
          const float key = tmp + swv;                     // fl(.. + sw)
          if (key < bk[ri] || (key == bk[ri] && code < bi[ri])) {
            bk[ri] = key; bi[ri] = code;
          }
        }
      }
    }
  }

  // Cross-thread min-merge: 16 code-groups per row -> pairwise via LDS.
  // First fold 16 -> 4 in registers... simplest: 2-stage via 4*MT buffers.
  __syncthreads();   // xs/ws done; reuse time for reduction arrays
  // stage 1: groups ct%4 write, then groups merge 4-way twice
  // (keep it simple: serialize into 4 slabs of MT, threads t<MT finish)
  {
    // each of 16 ct-groups writes its 4 rows into slab (ct & 3), max 4 rounds
#pragma unroll
    for (int ri = 0; ri < 4; ++ri) {
      const int row = rt * 4 + ri;
      if ((ct >> 2) == 0) { redk[(ct & 3) * MT + row] = bk[ri]; redi[(ct & 3) * MT + row] = bi[ri]; }
    }
    __syncthreads();
#pragma unroll
    for (int q = 1; q < 4; ++q) {
      if ((ct >> 2) == q) {
#pragma unroll
        for (int ri = 0; ri < 4; ++ri) {
          const int row = rt * 4 + ri;
          const int s = (ct & 3) * MT + row;
          const float kq = redk[s]; const int iq = redi[s];
          if (bk[ri] < kq || (bk[ri] == kq && bi[ri] < iq)) { redk[s] = bk[ri]; redi[s] = bi[ri]; }
        }
      }
      __syncthreads();
    }
  }
  if (t < MT) {
    float k0 = redk[t]; int i0 = redi[t];
#pragma unroll
    for (int q = 1; q < 4; ++q) {
      const float kq = redk[q * MT + t];
      const int   iq = redi[q * MT + t];
      if (kq < k0 || (kq == k0 && iq < i0)) { k0 = kq; i0 = iq; }
    }
    oidx[n0 + t] = (float)i0;   // idx output region read back as fp32
  }
}

// ---------------------------------------------------------------------------
// Epilogue: quantized gather + straight-through estimator.
// quantized[b,c,h,w] = w[idx[b,h,w]][c];  ste = fl(fl(q - x) + x).
// ---------------------------------------------------------------------------
__global__ void k_epilogue(const float* __restrict__ x, const float* __restrict__ w,
                           const float* __restrict__ oidx, float* __restrict__ out) {
#pragma clang fp contract(off)
  const int e  = blockIdx.x * blockDim.x + threadIdx.x;  // 0..4194303
  const int b  = e >> 16;
  const int c  = (e >> 8) & 255;
  const int hw = (e & 255) * 4;
  const size_t xoff = (size_t)(b * CODE_DIM + c) * HWSZ + hw;
  const int n = (b << 10) + hw;
  vf4 xv = *(const vf4*)(x + xoff);
  vf4 q, s;
#pragma unroll
  for (int u = 0; u < 4; ++u) {
    const int idx = (int)oidx[n + u];
    const float qv = w[(size_t)idx * CODE_DIM + c];
    q[u] = qv;
    const float d = qv - xv[u];
    s[u] = d + xv[u];
  }
  *(vf4*)(out + xoff) = q;
  *(vf4*)(out + (size_t)QELEMS + xoff) = s;
}

extern "C" void kernel_launch(void* const* d_in, const int* in_sizes, int n_in,
                              void* d_out, int out_size, void* d_ws, size_t ws_size,
                              hipStream_t stream) {
  const float* x = (const float*)d_in[0];   // (64,256,32,32) fp32
  const float* w = (const float*)d_in[1];   // (1024,256) fp32
  float* out  = (float*)d_out;
  float* oidx = out + 2 * (size_t)QELEMS;          // idx region (written as float)
  // scratch for sx/sw lives inside the ste region; epilogue overwrites it later
  float* sx = out + (size_t)QELEMS;                // 65536 floats
  float* sw = out + (size_t)QELEMS + NROWS;        // 1024 floats

  k_sumsq_w<<<CODE_SIZE / 256, 256, 0, stream>>>(w, sw);
  k_sumsq_x<<<NROWS / 256, 256, 0, stream>>>(x, sx);
  k_argmin<<<NROWS / MT, 256, 0, stream>>>(x, w, sx, sw, oidx);
  k_epilogue<<<QELEMS / 4 / 256, 256, 0, stream>>>(x, w, oidx, out);
}

// Round 3
// 615.099 us; speedup vs baseline: 1.5289x; 1.1478x over previous
//
#include <hip/hip_runtime.h>
#include <math.h>

typedef float vf4 __attribute__((ext_vector_type(4)));

#define CODE_SIZE 1024
#define CODE_DIM  256
#define BB        64
#define HWSZ      1024                       // H*W = 32*32
#define NROWS     (BB * HWSZ)                // 65536
#define QELEMS    (BB * CODE_DIM * HWSZ)     // 16777216

// ---------------------------------------------------------------------------
// sw[code] = numpy-pairwise sum of fl(w*w) over 256 contiguous elements.
// ---------------------------------------------------------------------------
__global__ void k_sumsq_w(const float* __restrict__ w, float* __restrict__ sw) {
#pragma clang fp contract(off)
  const int code = blockIdx.x * blockDim.x + threadIdx.x;
  if (code >= CODE_SIZE) return;
  const float* row = w + (size_t)code * CODE_DIM;
  float halves[2];
  for (int h = 0; h < 2; ++h) {
    const float* p = row + h * 128;
    float r[8];
#pragma unroll
    for (int j = 0; j < 8; ++j) { float v = p[j]; r[j] = v * v; }
    for (int i = 8; i < 128; i += 8) {
#pragma unroll
      for (int j = 0; j < 8; ++j) { float v = p[i + j]; r[j] += v * v; }
    }
    halves[h] = ((r[0] + r[1]) + (r[2] + r[3])) + ((r[4] + r[5]) + (r[6] + r[7]));
  }
  sw[code] = halves[0] + halves[1];
}

// sx[n] = same pairwise over fl(x*x), x strided by HWSZ along channel dim.
__global__ void k_sumsq_x(const float* __restrict__ x, float* __restrict__ sx) {
#pragma clang fp contract(off)
  const int n = blockIdx.x * blockDim.x + threadIdx.x;   // 0..65535
  const int b = n >> 10, hw = n & 1023;
  const float* p = x + (size_t)b * CODE_DIM * HWSZ + hw;
  float halves[2];
  for (int h = 0; h < 2; ++h) {
    const float* q = p + (size_t)(h * 128) * HWSZ;
    float r[8];
#pragma unroll
    for (int j = 0; j < 8; ++j) { float v = q[(size_t)j * HWSZ]; r[j] = v * v; }
    for (int i = 8; i < 128; i += 8) {
#pragma unroll
      for (int j = 0; j < 8; ++j) { float v = q[(size_t)(i + j) * HWSZ]; r[j] += v * v; }
    }
    halves[h] = ((r[0] + r[1]) + (r[2] + r[3])) + ((r[4] + r[5]) + (r[6] + r[7]));
  }
  sx[n] = halves[0] + halves[1];
}

// ---------------------------------------------------------------------------
// GEMM-argmin. Block = 64 rows x 256-code chunks (4 chunks), KC=32.
// Thread tile 8x8 -> 64 FMA per 4 ds_read_b128 (round-2's 4x4 was 16 FMA per
// 2 reads -> LDS-pipe-bound at VALUBusy 61%). Lanes: rt=t&7 rows, ct=t>>3
// codes -> both LDS reads are 8-way same-address broadcasts (conflict-free).
// Accumulator: single sequential fmaf chain over k=0..255 (chunk-outer,
// kc-inner) — bitwise-matching np's sgemm. Key = fl(fl(sx-2G)+sw), contract
// off. Tie-break lowest index everywhere (ascending scan + strict <).
// LDS: xs 8KB + ws 32KB = 40960 B -> 4 blocks/CU.
// ---------------------------------------------------------------------------
#define MT  64
#define NTC 256
#define NCH (CODE_SIZE / NTC)
#define KC  32

__launch_bounds__(256, 4)
__global__ void k_argmin(const float* __restrict__ x, const float* __restrict__ w,
                         const float* __restrict__ sx, const float* __restrict__ sw,
                         float* __restrict__ oidx) {
  __shared__ float xs[KC * MT];    // [k][r], 8 KB
  __shared__ float ws[KC * NTC];   // [k][code], 32 KB; overlaid by reduction

  const int t   = threadIdx.x;
  const int n0  = blockIdx.x * MT;
  const int b   = n0 >> 10;
  const int hw0 = n0 & 1023;
  const int rt  = t & 7;     // rows rt*8 .. rt*8+7
  const int ct  = t >> 3;    // code-group 0..31: codes ct*8..ct*8+7 per chunk

  float bk[8]; float bi[8];
#pragma unroll
  for (int ri = 0; ri < 8; ++ri) { bk[ri] = INFINITY; bi[ri] = (float)CODE_SIZE; }

  for (int chunk = 0; chunk < NCH; ++chunk) {
    const int code0 = chunk * NTC;

    float acc[8][8];
#pragma unroll
    for (int ri = 0; ri < 8; ++ri)
#pragma unroll
      for (int cj = 0; cj < 8; ++cj) acc[ri][cj] = 0.0f;

    for (int kc = 0; kc < CODE_DIM / KC; ++kc) {
      const int kbase = kc * KC;
      __syncthreads();   // protect xs/ws from previous stage's readers
      // stage xs[k][r]: 512 vf4 jobs, coalesced 256-B segments per k-row
      {
#pragma unroll
        for (int i = 0; i < 2; ++i) {
          const int j  = t + 256 * i;
          const int k  = j >> 4;      // 0..31
          const int rq = j & 15;      // row quad
          vf4 v = *(const vf4*)(x + ((size_t)(b * CODE_DIM + kbase + k) * HWSZ + hw0 + rq * 4));
          *(vf4*)(xs + k * MT + rq * 4) = v;
        }
      }
      // stage ws[k][code]: thread t owns code code0+t; row-contiguous global
      // reads (L1-friendly), LDS writes bank = code mod 32 -> conflict-free
      {
        const float* wr = w + (size_t)(code0 + t) * CODE_DIM + kbase;
#pragma unroll
        for (int q = 0; q < 8; ++q) {
          vf4 v = *(const vf4*)(wr + q * 4);
          ws[(q * 4 + 0) * NTC + t] = v.x;
          ws[(q * 4 + 1) * NTC + t] = v.y;
          ws[(q * 4 + 2) * NTC + t] = v.z;
          ws[(q * 4 + 3) * NTC + t] = v.w;
        }
      }
      __syncthreads();

      const float* xp = xs + rt * 8;
      const float* wp = ws + ct * 8;
#pragma unroll 4
      for (int k = 0; k < KC; ++k) {
        vf4 xv0 = *(const vf4*)(xp + k * MT);
        vf4 xv1 = *(const vf4*)(xp + k * MT + 4);
        vf4 wv0 = *(const vf4*)(wp + k * NTC);
        vf4 wv1 = *(const vf4*)(wp + k * NTC + 4);
        float xr[8] = {xv0.x, xv0.y, xv0.z, xv0.w, xv1.x, xv1.y, xv1.z, xv1.w};
        float wc[8] = {wv0.x, wv0.y, wv0.z, wv0.w, wv1.x, wv1.y, wv1.z, wv1.w};
#pragma unroll
        for (int ri = 0; ri < 8; ++ri)
#pragma unroll
          for (int cj = 0; cj < 8; ++cj)
            acc[ri][cj] = fmaf(xr[ri], wc[cj], acc[ri][cj]);
      }
    }

    // per-chunk min-merge (codes ascending -> lowest-index tie-break)
    {
#pragma clang fp contract(off)
      float sxr[8];
#pragma unroll
      for (int ri = 0; ri < 8; ++ri) sxr[ri] = sx[n0 + rt * 8 + ri];
#pragma unroll
      for (int cj = 0; cj < 8; ++cj) {
        const int code = code0 + ct * 8 + cj;
        const float swv = sw[code];
        const float codef = (float)code;
#pragma unroll
        for (int ri = 0; ri < 8; ++ri) {
          const float tmp = sxr[ri] - 2.0f * acc[ri][cj];  // fl(sx - 2G)
          const float key = tmp + swv;                     // fl(.. + sw)
          if (key < bk[ri] || (key == bk[ri] && codef < bi[ri])) {
            bk[ri] = key; bi[ri] = codef;
          }
        }
      }
    }
  }

  // cross-thread reduction: 32 code-group slabs per row, overlaid on ws
  __syncthreads();
  float* redk = ws;                    // 32*64 floats
  float* redi = ws + 32 * MT;          // 32*64 floats (codes as float, exact)
#pragma unroll
  for (int ri = 0; ri < 8; ++ri) {
    const int row = rt * 8 + ri;
    redk[ct * MT + row] = bk[ri];
    redi[ct * MT + row] = bi[ri];
  }
  __syncthreads();
  if (t < MT) {
    float k0 = redk[t]; float i0 = redi[t];
    for (int q = 1; q < 32; ++q) {     // ascending ct -> ascending codes
      const float kq = redk[q * MT + t];
      const float iq = redi[q * MT + t];
      if (kq < k0 || (kq == k0 && iq < i0)) { k0 = kq; i0 = iq; }
    }
    oidx[n0 + t] = i0;   // idx output region read back as fp32
  }
}

// ---------------------------------------------------------------------------
// Epilogue: block = (b, 64-hw tile). Stage the 64 gathered w-rows into LDS
// (wt[c][r], stride 65 -> 2-way banks, free), then fully-coalesced vf4
// global reads/writes for q and ste = fl(fl(q - x) + x).
// ---------------------------------------------------------------------------
#define WT_S 65

__global__ void k_epilogue(const float* __restrict__ x, const float* __restrict__ w,
                           const float* __restrict__ oidx, float* __restrict__ out) {
#pragma clang fp contract(off)
  __shared__ int   idxs[MT];
  __shared__ float wt[CODE_DIM * WT_S];   // wt[c][r], 66560 B

  const int t   = threadIdx.x;
  const int n0  = blockIdx.x * MT;
  const int b   = n0 >> 10;
  const int hw0 = n0 & 1023;

  if (t < MT) idxs[t] = (int)oidx[n0 + t];
  __syncthreads();

  // stage wt: jobs j -> (r = j&63, cq = j>>6); lanes span r -> per-lane 16-B
  // gathers from 64 w-rows (L1/L2 absorb; each row consumed fully by the
  // 4 sibling threads), LDS writes bank=(c+r)%32 with r spanning -> free.
#pragma unroll
  for (int i = 0; i < 16; ++i) {
    const int j  = t + 256 * i;
    const int r  = j & 63;
    const int cq = j >> 6;     // 0..63
    vf4 v = *(const vf4*)(w + (size_t)idxs[r] * CODE_DIM + cq * 4);
    wt[(cq * 4 + 0) * WT_S + r] = v.x;
    wt[(cq * 4 + 1) * WT_S + r] = v.y;
    wt[(cq * 4 + 2) * WT_S + r] = v.z;
    wt[(cq * 4 + 3) * WT_S + r] = v.w;
  }
  __syncthreads();

  // outputs: jobs j -> (c = j>>4, rq = j&15); global vf4 fully coalesced
#pragma unroll
  for (int i = 0; i < 16; ++i) {
    const int j  = t + 256 * i;
    const int c  = j >> 4;     // 0..255
    const int rq = j & 15;
    const size_t off = (size_t)(b * CODE_DIM + c) * HWSZ + hw0 + rq * 4;
    vf4 xv = *(const vf4*)(x + off);
    vf4 q, s;
#pragma unroll
    for (int u = 0; u < 4; ++u) {
      const float qv = wt[c * WT_S + rq * 4 + u];
      q[u] = qv;
      const float d = qv - xv[u];
      s[u] = d + xv[u];
    }
    *(vf4*)(out + off) = q;
    *(vf4*)(out + (size_t)QELEMS + off) = s;
  }
}

extern "C" void kernel_launch(void* const* d_in, const int* in_sizes, int n_in,
                              void* d_out, int out_size, void* d_ws, size_t ws_size,
                              hipStream_t stream) {
  const float* x = (const float*)d_in[0];   // (64,256,32,32) fp32
  const float* w = (const float*)d_in[1];   // (1024,256) fp32
  float* out  = (float*)d_out;
  float* oidx = out + 2 * (size_t)QELEMS;          // idx region (written as float)
  // scratch for sx/sw lives inside the ste region; epilogue (which runs after
  // k_argmin completes, stream-ordered) overwrites it later
  float* sx = out + (size_t)QELEMS;                // 65536 floats
  float* sw = out + (size_t)QELEMS + NROWS;        // 1024 floats

  k_sumsq_w<<<CODE_SIZE / 256, 256, 0, stream>>>(w, sw);
  k_sumsq_x<<<NROWS / 256, 256, 0, stream>>>(x, sx);
  k_argmin<<<NROWS / MT, 256, 0, stream>>>(x, w, sx, sw, oidx);
  k_epilogue<<<NROWS / MT, 256, 0, stream>>>(x, w, oidx, out);
}